// Round 13
// baseline (323.671 us; speedup 1.0000x reference)
//
#include <hip/hip_runtime.h>

// LSTM_26877905338550 — B=1048576 tiny-MLP LSTM chains, T=3.
// R13 = R12 with the cvt_pkrtz type fixed (builtin returns __fp16x2, not
// _Float16x2; bit_cast through int). Diet vs R11:
//  (a) quad-rcp: 4 tanh denominators share ONE v_rcp (product + 9 muls)
//  (b) v_cvt_pkrtz_f16_f32 packs (2 instr/frag vs 4 cvt + 2 pack)
//  (c) cell tanh -> deg-7 odd poly (cell provably bounded |c|<=1.27)
// Activations stay in C/D==B-operand layout (16x16x16f16); weights
// pre-swizzled to A-frag order in LDS; hidden crosses t via shfl_xor(32).

#define NB 1048576

typedef unsigned short u16t;
typedef __attribute__((ext_vector_type(2))) __fp16 fp16x2;
typedef __attribute__((ext_vector_type(4))) _Float16 half4;
typedef __attribute__((ext_vector_type(4))) float f32x4;
typedef __attribute__((ext_vector_type(2))) int int2v;

#define MFMA __builtin_amdgcn_mfma_f32_16x16x16f16
#define TSCL 2.8853900817779268f   // 2*log2(e)

#define NTILE 47
#define WFSZ (NTILE * 256)    // u16 elems = 12032 (24064 B)
#define BIASOFF (WFSZ / 2)    // float offset into ws = 6016
// bias block layout (floats)
#define BHS 0
#define BB0 32
#define BB1 64
#define BB2 112
#define BB3 160
#define BGB 192
#define BPW 320
#define BPB 352
#define NBIAS 360

__global__ void prep_kernel(const float* __restrict__ htW, const float* __restrict__ htb,
                            const float* __restrict__ w0,  const float* __restrict__ b0,
                            const float* __restrict__ w1,  const float* __restrict__ b1,
                            const float* __restrict__ w2,  const float* __restrict__ b2,
                            const float* __restrict__ w3,  const float* __restrict__ b3,
                            const float* __restrict__ gw,  const float* __restrict__ gb,
                            const float* __restrict__ p1w, const float* __restrict__ p1b,
                            const float* __restrict__ p2w, const float* __restrict__ p2b,
                            float* __restrict__ ws) {
  int tid = threadIdx.x;
  // A-fragment tiles: lane l holds (m = m0+(l&15), k = k0+(l>>4)*4+i), i=0..3
  const signed char msel[NTILE] = {0,0,0,0,0,0, 1,1,1,1, 2,2,2,2,2,2,
                                   3,3,3,3,3,3,3,3,3, 4,4,4,4,4,4,
                                   5,5,5,5,5,5,5,5, 5,5,5,5,5,5,5,5};
  const unsigned char tm0[NTILE] = {0,0,0,16,16,16, 0,0,16,16, 0,0,16,16,32,32,
                                    0,0,0,16,16,16,32,32,32, 0,0,0,16,16,16,
                                    0,0,32,32,64,64,96,96, 16,16,48,48,80,80,112,112};
  const unsigned char tk0[NTILE] = {0,16,32,0,16,32, 0,16,0,16, 0,16,0,16,0,16,
                                    0,16,32,0,16,32,0,16,32, 0,16,32,0,16,32,
                                    0,16,0,16,0,16,0,16, 0,16,0,16,0,16,0,16};
  u16t* wf = (u16t*)ws;
  for (int i = tid; i < WFSZ; i += 256) {
    int tau = i >> 8, s = i & 255, l = s >> 2, ii = s & 3;
    int k = tk0[tau] + ((l >> 4) << 2) + ii;
    float v = 0.f;
    int sel = msel[tau];
    if (sel == 5) {
      int g = tm0[tau] >> 5;
      int j = (tm0[tau] & 16) + (l & 15);
      if (j < 30 && k < 30) v = gw[(g * 30 + j) * 30 + k];
    } else {
      int m = tm0[tau] + (l & 15);
      switch (sel) {
        case 0: if (m < 30 && k < 38) v = htW[m * 38 + k]; break;
        case 1: if (m < 30 && k < 30) v = w0[m * 60 + k] + w0[m * 60 + 30 + k]; break;
        case 2: if (m < 45 && k < 30) v = w1[m * 30 + k]; break;
        case 3: if (m < 40 && k < 45) v = w2[m * 45 + k]; break;
        default: if (m < 30 && k < 40) v = w3[m * 40 + k]; break;
      }
    }
    if (tau >= 6) v *= TSCL;   // prescale all tanh-producing layers (L2..L5, gates)
    _Float16 h = (_Float16)v;
    wf[i] = __builtin_bit_cast(u16t, h);
  }
  float* bias = ws + BIASOFF;
  for (int i = tid; i < NBIAS; i += 256) {
    float v = 0.f;
    if (i < 32)       { if (i < 30) v = htb[i]; }
    else if (i < 64)  { int j = i - 32;  if (j < 30) v = b0[j]; }
    else if (i < 112) { int j = i - 64;  if (j < 45) v = b1[j]; }
    else if (i < 160) { int j = i - 112; if (j < 40) v = b2[j]; }
    else if (i < 192) { int j = i - 160; if (j < 30) v = b3[j]; }
    else if (i < 320) { int j = i - 192; int g = j >> 5, q = j & 31;
                        if (q < 30) v = gb[g * 30 + q]; }
    else if (i < 352) { int j = i - 320;
                        if (j < 30) { float a = 0.f;
                          for (int m = 0; m < 10; m++) a += p2w[m] * p1w[m * 30 + j];
                          v = a; } }
    else if (i == 352){ float a = p2b[0];
                        for (int m = 0; m < 10; m++) a += p2w[m] * p1b[m];
                        v = a; }
    if (i >= 32 && i < 320) v *= TSCL;   // prescale b0..b3, gate biases
    bias[i] = v;
  }
}

// pack 4 f32 -> half4 via 2x v_cvt_pkrtz_f16_f32
__device__ __forceinline__ half4 pk4(float a, float b, float c, float d) {
  fp16x2 lo = __builtin_amdgcn_cvt_pkrtz(a, b);
  fp16x2 hi = __builtin_amdgcn_cvt_pkrtz(c, d);
  int2v r = {__builtin_bit_cast(int, lo), __builtin_bit_cast(int, hi)};
  return __builtin_bit_cast(half4, r);
}

// 4x tanh of PRESCALED inputs with ONE v_rcp (quad denominator product)
__device__ __forceinline__ f32x4 qtanh(f32x4 y) {
  float u0 = __builtin_amdgcn_exp2f(y[0]);
  float u1 = __builtin_amdgcn_exp2f(y[1]);
  float u2 = __builtin_amdgcn_exp2f(y[2]);
  float u3 = __builtin_amdgcn_exp2f(y[3]);
  float D0 = u0 + 1.f, D1 = u1 + 1.f, D2 = u2 + 1.f, D3 = u3 + 1.f;
  float D01 = D0 * D1, D23 = D2 * D3;
  float v = __builtin_amdgcn_rcpf(D01 * D23);
  float v01 = v * D23, v23 = v * D01;
  f32x4 t;
  t[0] = fmaf(-2.f, v01 * D1, 1.f);
  t[1] = fmaf(-2.f, v01 * D0, 1.f);
  t[2] = fmaf(-2.f, v23 * D3, 1.f);
  t[3] = fmaf(-2.f, v23 * D2, 1.f);
  return t;
}

__device__ __forceinline__ half4 tp4(f32x4 c) {   // quad tanh -> pkrtz f16
  f32x4 t = qtanh(c);
  return pk4(t[0], t[1], t[2], t[3]);
}

// sigm(t), t in [-1,1]: odd minimax poly, err ~1e-5
__device__ __forceinline__ float psig(float t) {
  float t2 = t * t;
  float p = fmaf(t2, fmaf(t2, 0.001734f, -0.020646f), 0.249971f);
  return fmaf(t, p, 0.5f);
}
// tanh(t), t in [-1,1]: odd deg-7 poly, err <1e-4
__device__ __forceinline__ float ptanh(float t) {
  float t2 = t * t;
  float p = fmaf(t2, fmaf(t2, fmaf(t2, -0.022665f, 0.111808f), -0.326967f), 0.999418f);
  return t * p;
}
// tanh(c) for |c| <= 1.35 (cell state; bound proven |c3|<=1.27): deg-7 odd,
// interpolatory fit at {0.25,0.5,1.0,1.35}, err ~4e-4 (below f16 floor)
__device__ __forceinline__ float ctanh(float c) {
  float y = c * c;
  float p = fmaf(y, fmaf(y, fmaf(y, -0.0194316f, 0.109571f), -0.328327f), 0.999778f);
  return c * p;
}

__global__ void __launch_bounds__(256) lstm_main(const float* __restrict__ x,
                                                 const float* __restrict__ ws,
                                                 float* __restrict__ out) {
  __shared__ __align__(16) u16t wfL[WFSZ];
  __shared__ __align__(16) float biasL[NBIAS];
  int tid = threadIdx.x;
  {
    const float4* src = (const float4*)ws;
    for (int i = tid; i < WFSZ / 8; i += 256) ((float4*)wfL)[i] = src[i];
    for (int i = tid; i < NBIAS / 4; i += 256) ((float4*)biasL)[i] = src[WFSZ / 8 + i];
  }
  __syncthreads();

  int lane = tid & 63, wv = tid >> 6;
  int q = lane >> 4;
  int eb = blockIdx.x * 64 + wv * 16;
  int elem = eb + (lane & 15);

  auto ldW = [&](int tau) -> half4 {
    return __builtin_bit_cast(half4, *(const int2v*)((const char*)wfL + tau * 512 + lane * 8));
  };
  auto ldbias = [&](int boff, int mt) -> f32x4 {
    float4 bv = *(const float4*)&biasL[boff + mt * 16 + q * 4];
    return (f32x4){bv.x, bv.y, bv.z, bv.w};
  };

  half4 h0pk = (half4)0, h1pk = (half4)0;
  float cell0[4] = {0.f, 0.f, 0.f, 0.f}, cell1[4] = {0.f, 0.f, 0.f, 0.f};
  float hid0[4], hid1[4];

  for (int t = 0; t < 3; t++) {
    // B-frags for L1 input [x(8); h(30); pad] (weight k-cols >=38 are zero)
    float4 xv = *(const float4*)(x + (size_t)elem * 24 + t * 8 + (q & 1) * 4);
    half4 hx = pk4(xv.x, xv.y, xv.z, xv.w);
    int2v h0i = __builtin_bit_cast(int2v, h0pk);
    int2v h1i = __builtin_bit_cast(int2v, h1pk);
    int2v sh0 = {__shfl_xor(h0i.x, 32), __shfl_xor(h0i.y, 32)};
    int2v sh1 = {__shfl_xor(h1i.x, 32), __shfl_xor(h1i.y, 32)};
    half4 B0 = (q < 2) ? hx : __builtin_bit_cast(half4, sh0);
    half4 B1 = __builtin_bit_cast(half4, (q < 2) ? sh0 : sh1);
    half4 B2 = __builtin_bit_cast(half4, sh1);

    // L1: hs[30] = WxWh @ [x;h] + ht_b      (2 m-tiles x 3 k-tiles), LINEAR
    f32x4 c0 = ldbias(BHS, 0), c1 = ldbias(BHS, 1);
    c0 = MFMA(ldW(0), B0, c0, 0, 0, 0);
    c0 = MFMA(ldW(1), B1, c0, 0, 0, 0);
    c0 = MFMA(ldW(2), B2, c0, 0, 0, 0);
    c1 = MFMA(ldW(3), B0, c1, 0, 0, 0);
    c1 = MFMA(ldW(4), B1, c1, 0, 0, 0);
    c1 = MFMA(ldW(5), B2, c1, 0, 0, 0);
    half4 f0 = pk4(c0[0], c0[1], c0[2], c0[3]);   // hs stays linear
    half4 f1 = pk4(c1[0], c1[1], c1[2], c1[3]);

    // L2: a0 = tanh(W0'~ @ hs + b0~)        (2 x 2), prescaled
    c0 = ldbias(BB0, 0); c1 = ldbias(BB0, 1);
    c0 = MFMA(ldW(6), f0, c0, 0, 0, 0);
    c0 = MFMA(ldW(7), f1, c0, 0, 0, 0);
    c1 = MFMA(ldW(8), f0, c1, 0, 0, 0);
    c1 = MFMA(ldW(9), f1, c1, 0, 0, 0);
    half4 g0 = tp4(c0), g1 = tp4(c1);

    // L3: a1                                 (3 x 2), prescaled
    f32x4 d0 = ldbias(BB1, 0), d1 = ldbias(BB1, 1), d2 = ldbias(BB1, 2);
    d0 = MFMA(ldW(10), g0, d0, 0, 0, 0);
    d0 = MFMA(ldW(11), g1, d0, 0, 0, 0);
    d1 = MFMA(ldW(12), g0, d1, 0, 0, 0);
    d1 = MFMA(ldW(13), g1, d1, 0, 0, 0);
    d2 = MFMA(ldW(14), g0, d2, 0, 0, 0);
    d2 = MFMA(ldW(15), g1, d2, 0, 0, 0);
    half4 e0 = tp4(d0), e1 = tp4(d1), e2 = tp4(d2);

    // L4: a2                                 (3 x 3), prescaled
    f32x4 u0 = ldbias(BB2, 0), u1 = ldbias(BB2, 1), u2 = ldbias(BB2, 2);
    u0 = MFMA(ldW(16), e0, u0, 0, 0, 0);
    u0 = MFMA(ldW(17), e1, u0, 0, 0, 0);
    u0 = MFMA(ldW(18), e2, u0, 0, 0, 0);
    u1 = MFMA(ldW(19), e0, u1, 0, 0, 0);
    u1 = MFMA(ldW(20), e1, u1, 0, 0, 0);
    u1 = MFMA(ldW(21), e2, u1, 0, 0, 0);
    u2 = MFMA(ldW(22), e0, u2, 0, 0, 0);
    u2 = MFMA(ldW(23), e1, u2, 0, 0, 0);
    u2 = MFMA(ldW(24), e2, u2, 0, 0, 0);
    half4 v0 = tp4(u0), v1 = tp4(u1), v2 = tp4(u2);

    // L5: a3                                 (2 x 3), prescaled
    c0 = ldbias(BB3, 0); c1 = ldbias(BB3, 1);
    c0 = MFMA(ldW(25), v0, c0, 0, 0, 0);
    c0 = MFMA(ldW(26), v1, c0, 0, 0, 0);
    c0 = MFMA(ldW(27), v2, c0, 0, 0, 0);
    c1 = MFMA(ldW(28), v0, c1, 0, 0, 0);
    c1 = MFMA(ldW(29), v1, c1, 0, 0, 0);
    c1 = MFMA(ldW(30), v2, c1, 0, 0, 0);
    half4 w0f = tp4(c0), w1f = tp4(c1);

    // L6 gates, j-tile 0 (j 0..15), prescaled pre-activations
    f32x4 ai = ldbias(BGB + 0, 0), af = ldbias(BGB + 32, 0);
    f32x4 ao = ldbias(BGB + 64, 0), ag = ldbias(BGB + 96, 0);
    ai = MFMA(ldW(31), w0f, ai, 0, 0, 0); ai = MFMA(ldW(32), w1f, ai, 0, 0, 0);
    af = MFMA(ldW(33), w0f, af, 0, 0, 0); af = MFMA(ldW(34), w1f, af, 0, 0, 0);
    ao = MFMA(ldW(35), w0f, ao, 0, 0, 0); ao = MFMA(ldW(36), w1f, ao, 0, 0, 0);
    ag = MFMA(ldW(37), w0f, ag, 0, 0, 0); ag = MFMA(ldW(38), w1f, ag, 0, 0, 0);
#pragma unroll
    for (int r = 0; r < 4; r++) {
      f32x4 tq = qtanh((f32x4){ai[r], af[r], ao[r], ag[r]});
      float ig = psig(tq[0]), fg = psig(tq[1]), og = psig(tq[2]);
      float gg = ptanh(tq[3]);
      float c = fmaf(fg, cell0[r], ig * gg);
      cell0[r] = c;
      hid0[r] = og * ctanh(c);
    }
    // L6 gates, j-tile 1 (j 16..29)
    ai = ldbias(BGB + 0, 1); af = ldbias(BGB + 32, 1);
    ao = ldbias(BGB + 64, 1); ag = ldbias(BGB + 96, 1);
    ai = MFMA(ldW(39), w0f, ai, 0, 0, 0); ai = MFMA(ldW(40), w1f, ai, 0, 0, 0);
    af = MFMA(ldW(41), w0f, af, 0, 0, 0); af = MFMA(ldW(42), w1f, af, 0, 0, 0);
    ao = MFMA(ldW(43), w0f, ao, 0, 0, 0); ao = MFMA(ldW(44), w1f, ao, 0, 0, 0);
    ag = MFMA(ldW(45), w0f, ag, 0, 0, 0); ag = MFMA(ldW(46), w1f, ag, 0, 0, 0);
#pragma unroll
    for (int r = 0; r < 4; r++) {
      f32x4 tq = qtanh((f32x4){ai[r], af[r], ao[r], ag[r]});
      float ig = psig(tq[0]), fg = psig(tq[1]), og = psig(tq[2]);
      float gg = ptanh(tq[3]);
      float c = fmaf(fg, cell1[r], ig * gg);
      cell1[r] = c;
      hid1[r] = og * ctanh(c);
    }
    // pack hidden for next t
    h0pk = pk4(hid0[0], hid0[1], hid0[2], hid0[3]);
    h1pk = pk4(hid1[0], hid1[1], hid1[2], hid1[3]);
  }
  // head: out[e] = pb + sum_j pW[j] * hid[j]   (pW zero-padded j>=30)
  float4 pw0 = *(const float4*)&biasL[BPW + q * 4];
  float4 pw1 = *(const float4*)&biasL[BPW + 16 + q * 4];
  float s = pw0.x * hid0[0] + pw0.y * hid0[1] + pw0.z * hid0[2] + pw0.w * hid0[3]
          + pw1.x * hid1[0] + pw1.y * hid1[1] + pw1.z * hid1[2] + pw1.w * hid1[3];
  s += __shfl_xor(s, 16);
  s += __shfl_xor(s, 32);
  if (lane < 16) out[eb + lane] = biasL[BPB] + s;
}

extern "C" void kernel_launch(void* const* d_in, const int* in_sizes, int n_in,
                              void* d_out, int out_size, void* d_ws, size_t ws_size,
                              hipStream_t stream) {
  const float* x   = (const float*)d_in[0];
  const float* htW = (const float*)d_in[1];
  const float* htb = (const float*)d_in[2];
  const float* w0  = (const float*)d_in[3];
  const float* b0  = (const float*)d_in[4];
  const float* w1  = (const float*)d_in[5];
  const float* b1  = (const float*)d_in[6];
  const float* w2  = (const float*)d_in[7];
  const float* b2  = (const float*)d_in[8];
  const float* w3  = (const float*)d_in[9];
  const float* b3  = (const float*)d_in[10];
  const float* gw  = (const float*)d_in[11];
  const float* gb  = (const float*)d_in[12];
  const float* p1w = (const float*)d_in[13];
  const float* p1b = (const float*)d_in[14];
  const float* p2w = (const float*)d_in[15];
  const float* p2b = (const float*)d_in[16];
  float* ws = (float*)d_ws;
  float* out = (float*)d_out;

  hipLaunchKernelGGL(prep_kernel, dim3(1), dim3(256), 0, stream,
                     htW, htb, w0, b0, w1, b1, w2, b2, w3, b3, gw, gb,
                     p1w, p1b, p2w, p2b, ws);
  hipLaunchKernelGGL(lstm_main, dim3(NB / 64), dim3(256), 0, stream, x, ws, out);
}

// Round 14
// 303.778 us; speedup vs baseline: 1.0655x; 1.0655x over previous
//
#include <hip/hip_runtime.h>

// LSTM_26877905338550 — B=1048576 tiny-MLP LSTM chains, T=3.
// R14 = R11 (best verified: 327us rocprof; per-value etanh, gate polys,
// cell ftanh) + ONLY the pkrtz pack from R13 (6 instr -> 2 per fragment,
// no chain lengthening). R13's quad-rcp reverted: it moved rcp work onto
// the congested VALU issue port (+9 mul/quad, longer dep chain) -> -8%.
// Zero-LDS-bounce MFMA pipeline: activations stay in C/D==B-operand
// layout (16x16x16f16); weights pre-swizzled to A-frag order in LDS;
// hidden crosses t via shfl_xor(32).

#define NB 1048576

typedef unsigned short u16t;
typedef __attribute__((ext_vector_type(2))) __fp16 fp16x2;
typedef __attribute__((ext_vector_type(4))) _Float16 half4;
typedef __attribute__((ext_vector_type(4))) float f32x4;
typedef __attribute__((ext_vector_type(2))) int int2v;

#define MFMA __builtin_amdgcn_mfma_f32_16x16x16f16
#define TSCL 2.8853900817779268f   // 2*log2(e)

#define NTILE 47
#define WFSZ (NTILE * 256)    // u16 elems = 12032 (24064 B)
#define BIASOFF (WFSZ / 2)    // float offset into ws = 6016
// bias block layout (floats)
#define BHS 0
#define BB0 32
#define BB1 64
#define BB2 112
#define BB3 160
#define BGB 192
#define BPW 320
#define BPB 352
#define NBIAS 360

__global__ void prep_kernel(const float* __restrict__ htW, const float* __restrict__ htb,
                            const float* __restrict__ w0,  const float* __restrict__ b0,
                            const float* __restrict__ w1,  const float* __restrict__ b1,
                            const float* __restrict__ w2,  const float* __restrict__ b2,
                            const float* __restrict__ w3,  const float* __restrict__ b3,
                            const float* __restrict__ gw,  const float* __restrict__ gb,
                            const float* __restrict__ p1w, const float* __restrict__ p1b,
                            const float* __restrict__ p2w, const float* __restrict__ p2b,
                            float* __restrict__ ws) {
  int tid = threadIdx.x;
  // A-fragment tiles: lane l holds (m = m0+(l&15), k = k0+(l>>4)*4+i), i=0..3
  const signed char msel[NTILE] = {0,0,0,0,0,0, 1,1,1,1, 2,2,2,2,2,2,
                                   3,3,3,3,3,3,3,3,3, 4,4,4,4,4,4,
                                   5,5,5,5,5,5,5,5, 5,5,5,5,5,5,5,5};
  const unsigned char tm0[NTILE] = {0,0,0,16,16,16, 0,0,16,16, 0,0,16,16,32,32,
                                    0,0,0,16,16,16,32,32,32, 0,0,0,16,16,16,
                                    0,0,32,32,64,64,96,96, 16,16,48,48,80,80,112,112};
  const unsigned char tk0[NTILE] = {0,16,32,0,16,32, 0,16,0,16, 0,16,0,16,0,16,
                                    0,16,32,0,16,32,0,16,32, 0,16,32,0,16,32,
                                    0,16,0,16,0,16,0,16, 0,16,0,16,0,16,0,16};
  u16t* wf = (u16t*)ws;
  for (int i = tid; i < WFSZ; i += 256) {
    int tau = i >> 8, s = i & 255, l = s >> 2, ii = s & 3;
    int k = tk0[tau] + ((l >> 4) << 2) + ii;
    float v = 0.f;
    int sel = msel[tau];
    if (sel == 5) {
      int g = tm0[tau] >> 5;
      int j = (tm0[tau] & 16) + (l & 15);
      if (j < 30 && k < 30) v = gw[(g * 30 + j) * 30 + k];
    } else {
      int m = tm0[tau] + (l & 15);
      switch (sel) {
        case 0: if (m < 30 && k < 38) v = htW[m * 38 + k]; break;
        case 1: if (m < 30 && k < 30) v = w0[m * 60 + k] + w0[m * 60 + 30 + k]; break;
        case 2: if (m < 45 && k < 30) v = w1[m * 30 + k]; break;
        case 3: if (m < 40 && k < 45) v = w2[m * 45 + k]; break;
        default: if (m < 30 && k < 40) v = w3[m * 40 + k]; break;
      }
    }
    if (tau >= 6) v *= TSCL;   // prescale all tanh-producing layers (L2..L5, gates)
    _Float16 h = (_Float16)v;
    wf[i] = __builtin_bit_cast(u16t, h);
  }
  float* bias = ws + BIASOFF;
  for (int i = tid; i < NBIAS; i += 256) {
    float v = 0.f;
    if (i < 32)       { if (i < 30) v = htb[i]; }
    else if (i < 64)  { int j = i - 32;  if (j < 30) v = b0[j]; }
    else if (i < 112) { int j = i - 64;  if (j < 45) v = b1[j]; }
    else if (i < 160) { int j = i - 112; if (j < 40) v = b2[j]; }
    else if (i < 192) { int j = i - 160; if (j < 30) v = b3[j]; }
    else if (i < 320) { int j = i - 192; int g = j >> 5, q = j & 31;
                        if (q < 30) v = gb[g * 30 + q]; }
    else if (i < 352) { int j = i - 320;
                        if (j < 30) { float a = 0.f;
                          for (int m = 0; m < 10; m++) a += p2w[m] * p1w[m * 30 + j];
                          v = a; } }
    else if (i == 352){ float a = p2b[0];
                        for (int m = 0; m < 10; m++) a += p2w[m] * p1b[m];
                        v = a; }
    if (i >= 32 && i < 320) v *= TSCL;   // prescale b0..b3, gate biases
    bias[i] = v;
  }
}

// tanh for PRESCALED input y = 2*log2e*x: 1 - 2/(exp2(y)+1)
__device__ __forceinline__ float etanh(float y) {
  float u = __builtin_amdgcn_exp2f(y);
  return 1.0f - 2.0f * __builtin_amdgcn_rcpf(u + 1.0f);
}
// tanh for plain input (cell state)
__device__ __forceinline__ float ftanh(float v) {
  float u = __builtin_amdgcn_exp2f(v * TSCL);
  return 1.0f - 2.0f * __builtin_amdgcn_rcpf(u + 1.0f);
}
// sigm(t), t in [-1,1]: odd minimax poly, err ~1e-5
__device__ __forceinline__ float psig(float t) {
  float t2 = t * t;
  float p = fmaf(t2, fmaf(t2, 0.001734f, -0.020646f), 0.249971f);
  return fmaf(t, p, 0.5f);
}
// tanh(t), t in [-1,1]: odd deg-7 poly, err <1e-4
__device__ __forceinline__ float ptanh(float t) {
  float t2 = t * t;
  float p = fmaf(t2, fmaf(t2, fmaf(t2, -0.022665f, 0.111808f), -0.326967f), 0.999418f);
  return t * p;
}

// pack 4 f32 -> half4 via 2x v_cvt_pkrtz_f16_f32
__device__ __forceinline__ half4 pk4(float a, float b, float c, float d) {
  fp16x2 lo = __builtin_amdgcn_cvt_pkrtz(a, b);
  fp16x2 hi = __builtin_amdgcn_cvt_pkrtz(c, d);
  int2v r = {__builtin_bit_cast(int, lo), __builtin_bit_cast(int, hi)};
  return __builtin_bit_cast(half4, r);
}

__device__ __forceinline__ half4 tp4(f32x4 c) {   // etanh -> pkrtz f16
  return pk4(etanh(c[0]), etanh(c[1]), etanh(c[2]), etanh(c[3]));
}

__global__ void __launch_bounds__(256) lstm_main(const float* __restrict__ x,
                                                 const float* __restrict__ ws,
                                                 float* __restrict__ out) {
  __shared__ __align__(16) u16t wfL[WFSZ];
  __shared__ __align__(16) float biasL[NBIAS];
  int tid = threadIdx.x;
  {
    const float4* src = (const float4*)ws;
    for (int i = tid; i < WFSZ / 8; i += 256) ((float4*)wfL)[i] = src[i];
    for (int i = tid; i < NBIAS / 4; i += 256) ((float4*)biasL)[i] = src[WFSZ / 8 + i];
  }
  __syncthreads();

  int lane = tid & 63, wv = tid >> 6;
  int q = lane >> 4;
  int eb = blockIdx.x * 64 + wv * 16;
  int elem = eb + (lane & 15);

  auto ldW = [&](int tau) -> half4 {
    return __builtin_bit_cast(half4, *(const int2v*)((const char*)wfL + tau * 512 + lane * 8));
  };
  auto ldbias = [&](int boff, int mt) -> f32x4 {
    float4 bv = *(const float4*)&biasL[boff + mt * 16 + q * 4];
    return (f32x4){bv.x, bv.y, bv.z, bv.w};
  };

  half4 h0pk = (half4)0, h1pk = (half4)0;
  float cell0[4] = {0.f, 0.f, 0.f, 0.f}, cell1[4] = {0.f, 0.f, 0.f, 0.f};
  float hid0[4], hid1[4];

  for (int t = 0; t < 3; t++) {
    // B-frags for L1 input [x(8); h(30); pad] (weight k-cols >=38 are zero)
    float4 xv = *(const float4*)(x + (size_t)elem * 24 + t * 8 + (q & 1) * 4);
    half4 hx = pk4(xv.x, xv.y, xv.z, xv.w);
    int2v h0i = __builtin_bit_cast(int2v, h0pk);
    int2v h1i = __builtin_bit_cast(int2v, h1pk);
    int2v sh0 = {__shfl_xor(h0i.x, 32), __shfl_xor(h0i.y, 32)};
    int2v sh1 = {__shfl_xor(h1i.x, 32), __shfl_xor(h1i.y, 32)};
    half4 B0 = (q < 2) ? hx : __builtin_bit_cast(half4, sh0);
    half4 B1 = __builtin_bit_cast(half4, (q < 2) ? sh0 : sh1);
    half4 B2 = __builtin_bit_cast(half4, sh1);

    // L1: hs[30] = WxWh @ [x;h] + ht_b      (2 m-tiles x 3 k-tiles), LINEAR
    f32x4 c0 = ldbias(BHS, 0), c1 = ldbias(BHS, 1);
    c0 = MFMA(ldW(0), B0, c0, 0, 0, 0);
    c0 = MFMA(ldW(1), B1, c0, 0, 0, 0);
    c0 = MFMA(ldW(2), B2, c0, 0, 0, 0);
    c1 = MFMA(ldW(3), B0, c1, 0, 0, 0);
    c1 = MFMA(ldW(4), B1, c1, 0, 0, 0);
    c1 = MFMA(ldW(5), B2, c1, 0, 0, 0);
    half4 f0 = pk4(c0[0], c0[1], c0[2], c0[3]);   // hs stays linear
    half4 f1 = pk4(c1[0], c1[1], c1[2], c1[3]);

    // L2: a0 = tanh(W0'~ @ hs + b0~)        (2 x 2), prescaled
    c0 = ldbias(BB0, 0); c1 = ldbias(BB0, 1);
    c0 = MFMA(ldW(6), f0, c0, 0, 0, 0);
    c0 = MFMA(ldW(7), f1, c0, 0, 0, 0);
    c1 = MFMA(ldW(8), f0, c1, 0, 0, 0);
    c1 = MFMA(ldW(9), f1, c1, 0, 0, 0);
    half4 g0 = tp4(c0), g1 = tp4(c1);

    // L3: a1                                 (3 x 2), prescaled
    f32x4 d0 = ldbias(BB1, 0), d1 = ldbias(BB1, 1), d2 = ldbias(BB1, 2);
    d0 = MFMA(ldW(10), g0, d0, 0, 0, 0);
    d0 = MFMA(ldW(11), g1, d0, 0, 0, 0);
    d1 = MFMA(ldW(12), g0, d1, 0, 0, 0);
    d1 = MFMA(ldW(13), g1, d1, 0, 0, 0);
    d2 = MFMA(ldW(14), g0, d2, 0, 0, 0);
    d2 = MFMA(ldW(15), g1, d2, 0, 0, 0);
    half4 e0 = tp4(d0), e1 = tp4(d1), e2 = tp4(d2);

    // L4: a2                                 (3 x 3), prescaled
    f32x4 u0 = ldbias(BB2, 0), u1 = ldbias(BB2, 1), u2 = ldbias(BB2, 2);
    u0 = MFMA(ldW(16), e0, u0, 0, 0, 0);
    u0 = MFMA(ldW(17), e1, u0, 0, 0, 0);
    u0 = MFMA(ldW(18), e2, u0, 0, 0, 0);
    u1 = MFMA(ldW(19), e0, u1, 0, 0, 0);
    u1 = MFMA(ldW(20), e1, u1, 0, 0, 0);
    u1 = MFMA(ldW(21), e2, u1, 0, 0, 0);
    u2 = MFMA(ldW(22), e0, u2, 0, 0, 0);
    u2 = MFMA(ldW(23), e1, u2, 0, 0, 0);
    u2 = MFMA(ldW(24), e2, u2, 0, 0, 0);
    half4 v0 = tp4(u0), v1 = tp4(u1), v2 = tp4(u2);

    // L5: a3                                 (2 x 3), prescaled
    c0 = ldbias(BB3, 0); c1 = ldbias(BB3, 1);
    c0 = MFMA(ldW(25), v0, c0, 0, 0, 0);
    c0 = MFMA(ldW(26), v1, c0, 0, 0, 0);
    c0 = MFMA(ldW(27), v2, c0, 0, 0, 0);
    c1 = MFMA(ldW(28), v0, c1, 0, 0, 0);
    c1 = MFMA(ldW(29), v1, c1, 0, 0, 0);
    c1 = MFMA(ldW(30), v2, c1, 0, 0, 0);
    half4 w0f = tp4(c0), w1f = tp4(c1);

    // L6 gates, j-tile 0 (j 0..15), prescaled pre-activations
    f32x4 ai = ldbias(BGB + 0, 0), af = ldbias(BGB + 32, 0);
    f32x4 ao = ldbias(BGB + 64, 0), ag = ldbias(BGB + 96, 0);
    ai = MFMA(ldW(31), w0f, ai, 0, 0, 0); ai = MFMA(ldW(32), w1f, ai, 0, 0, 0);
    af = MFMA(ldW(33), w0f, af, 0, 0, 0); af = MFMA(ldW(34), w1f, af, 0, 0, 0);
    ao = MFMA(ldW(35), w0f, ao, 0, 0, 0); ao = MFMA(ldW(36), w1f, ao, 0, 0, 0);
    ag = MFMA(ldW(37), w0f, ag, 0, 0, 0); ag = MFMA(ldW(38), w1f, ag, 0, 0, 0);
#pragma unroll
    for (int r = 0; r < 4; r++) {
      float ti = etanh(ai[r]), tf = etanh(af[r]);
      float to = etanh(ao[r]), tg = etanh(ag[r]);
      float ig = psig(ti), fg = psig(tf), og = psig(to);
      float gg = ptanh(tg);
      float c = fmaf(fg, cell0[r], ig * gg);
      cell0[r] = c;
      hid0[r] = og * ftanh(c);
    }
    // L6 gates, j-tile 1 (j 16..29)
    ai = ldbias(BGB + 0, 1); af = ldbias(BGB + 32, 1);
    ao = ldbias(BGB + 64, 1); ag = ldbias(BGB + 96, 1);
    ai = MFMA(ldW(39), w0f, ai, 0, 0, 0); ai = MFMA(ldW(40), w1f, ai, 0, 0, 0);
    af = MFMA(ldW(41), w0f, af, 0, 0, 0); af = MFMA(ldW(42), w1f, af, 0, 0, 0);
    ao = MFMA(ldW(43), w0f, ao, 0, 0, 0); ao = MFMA(ldW(44), w1f, ao, 0, 0, 0);
    ag = MFMA(ldW(45), w0f, ag, 0, 0, 0); ag = MFMA(ldW(46), w1f, ag, 0, 0, 0);
#pragma unroll
    for (int r = 0; r < 4; r++) {
      float ti = etanh(ai[r]), tf = etanh(af[r]);
      float to = etanh(ao[r]), tg = etanh(ag[r]);
      float ig = psig(ti), fg = psig(tf), og = psig(to);
      float gg = ptanh(tg);
      float c = fmaf(fg, cell1[r], ig * gg);
      cell1[r] = c;
      hid1[r] = og * ftanh(c);
    }
    // pack hidden for next t
    h0pk = pk4(hid0[0], hid0[1], hid0[2], hid0[3]);
    h1pk = pk4(hid1[0], hid1[1], hid1[2], hid1[3]);
  }
  // head: out[e] = pb + sum_j pW[j] * hid[j]   (pW zero-padded j>=30)
  float4 pw0 = *(const float4*)&biasL[BPW + q * 4];
  float4 pw1 = *(const float4*)&biasL[BPW + 16 + q * 4];
  float s = pw0.x * hid0[0] + pw0.y * hid0[1] + pw0.z * hid0[2] + pw0.w * hid0[3]
          + pw1.x * hid1[0] + pw1.y * hid1[1] + pw1.z * hid1[2] + pw1.w * hid1[3];
  s += __shfl_xor(s, 16);
  s += __shfl_xor(s, 32);
  if (lane < 16) out[eb + lane] = biasL[BPB] + s;
}

extern "C" void kernel_launch(void* const* d_in, const int* in_sizes, int n_in,
                              void* d_out, int out_size, void* d_ws, size_t ws_size,
                              hipStream_t stream) {
  const float* x   = (const float*)d_in[0];
  const float* htW = (const float*)d_in[1];
  const float* htb = (const float*)d_in[2];
  const float* w0  = (const float*)d_in[3];
  const float* b0  = (const float*)d_in[4];
  const float* w1  = (const float*)d_in[5];
  const float* b1  = (const float*)d_in[6];
  const float* w2  = (const float*)d_in[7];
  const float* b2  = (const float*)d_in[8];
  const float* w3  = (const float*)d_in[9];
  const float* b3  = (const float*)d_in[10];
  const float* gw  = (const float*)d_in[11];
  const float* gb  = (const float*)d_in[12];
  const float* p1w = (const float*)d_in[13];
  const float* p1b = (const float*)d_in[14];
  const float* p2w = (const float*)d_in[15];
  const float* p2b = (const float*)d_in[16];
  float* ws = (float*)d_ws;
  float* out = (float*)d_out;

  hipLaunchKernelGGL(prep_kernel, dim3(1), dim3(256), 0, stream,
                     htW, htb, w0, b0, w1, b1, w2, b2, w3, b3, gw, gb,
                     p1w, p1b, p2w, p2b, ws);
  hipLaunchKernelGGL(lstm_main, dim3(NB / 64), dim3(256), 0, stream, x, ws, out);
}